// Round 11
// baseline (148.746 us; speedup 1.0000x reference)
//
#include <hip/hip_runtime.h>
#include <hip/hip_bf16.h>

// ---------- types ----------
typedef __attribute__((ext_vector_type(4)))  float f32x4;
typedef __attribute__((ext_vector_type(16))) float f32x16;
typedef __attribute__((ext_vector_type(8)))  short bf16x8;   // 8 bf16 in 4 VGPRs
typedef unsigned short u16;
typedef unsigned int   u32;
typedef unsigned long long u64;
typedef __attribute__((ext_vector_type(2))) u32 u32x2;
typedef __attribute__((ext_vector_type(4))) u32 u32x4;

#define S_LEN 2048
#define HID   2048
#define NH    16
#define NKV   4
#define HD    128
#define DKV   512          // NKV*HD
#define QK_SCALE 0.08838834764831845f   // 1/sqrt(128)

__device__ __forceinline__ u16 f2bf(float x) {              // RNE f32 -> bf16 bits
    u32 u = __builtin_bit_cast(u32, x);
    u32 r = (u + 0x7fffu + ((u >> 16) & 1u)) >> 16;
    return (u16)r;
}
__device__ __forceinline__ float bf2f(u16 b) {
    u32 u = ((u32)b) << 16;
    return __builtin_bit_cast(float, u);
}
__device__ __forceinline__ void gload_lds16(const void* g, void* l) {
    __builtin_amdgcn_global_load_lds(
        (const __attribute__((address_space(1))) u32*)g,
        (__attribute__((address_space(3))) u32*)l, 16, 0, 0);
}
__device__ __forceinline__ u32x4 pack8(const u16* o) {
    u32x4 r;
    r[0] = (u32)o[0] | ((u32)o[1] << 16);
    r[1] = (u32)o[2] | ((u32)o[3] << 16);
    r[2] = (u32)o[4] | ((u32)o[5] << 16);
    r[3] = (u32)o[6] | ((u32)o[7] << 16);
    return r;
}

// lane pair (L, L^32) exchange: x0/x1 per v_permlane32_swap semantics
__device__ __forceinline__ void plswap(u32 a, u32 b, u32& x0, u32& x1) {
#if __has_builtin(__builtin_amdgcn_permlane32_swap)
    u32x2 r = __builtin_amdgcn_permlane32_swap(a, b, false, false);
    x0 = r[0]; x1 = r[1];
#else
    u32 oa = (u32)__shfl_xor((int)a, 32);
    u32 ob = (u32)__shfl_xor((int)b, 32);
    int hi = (threadIdx.x & 63) >> 5;
    x0 = hi ? ob : a;
    x1 = hi ? b : oa;
#endif
}
__device__ __forceinline__ float pairmax32(float v) {
    u32 x0, x1; plswap(__builtin_bit_cast(u32, v), __builtin_bit_cast(u32, v), x0, x1);
    return fmaxf(__builtin_bit_cast(float, x0), __builtin_bit_cast(float, x1));
}
__device__ __forceinline__ float pairsum32(float v) {
    u32 x0, x1; plswap(__builtin_bit_cast(u32, v), __builtin_bit_cast(u32, v), x0, x1);
    return __builtin_bit_cast(float, x0) + __builtin_bit_cast(float, x1);
}

// ================= fused preprocessing (unchanged) =================
#define NTQ 1024
#define NTK 256
#define NTV 256
#define NTO 1024
#define NT_W (NTQ + NTK + NTV + NTO)          // 2560
#define NB_CVT 1024
#define NB_START 128
#define NB_PREP (NT_W + NB_CVT + NB_START)    // 3712

__global__ __launch_bounds__(256) void prep_kernel(
        const u32* __restrict__ X, const unsigned char* __restrict__ mask,
        const void* __restrict__ Wq, const void* __restrict__ Wk,
        const void* __restrict__ Wv, const void* __restrict__ Wo,
        u16* __restrict__ Xbf, u16* __restrict__ WqT, u16* __restrict__ WkT,
        u16* __restrict__ WvT, u16* __restrict__ WoT, int* __restrict__ start)
{
    __shared__ float tile[64][65];
    const int tid = threadIdx.x, lane = tid & 63, wave = tid >> 6;

    int big = 0, nz = 0;
    #pragma unroll
    for (int i = 0; i < 4; i++) {
        u32 v = X[lane + i * 64];
        u16 lo = (u16)(v & 0xffffu);
        int e = (lo >> 7) & 0xff;
        big |= (e >= 0x83);
        nz  |= (lo != 0);
    }
    const int isf32 = (__ballot(big) != 0ull || __ballot(nz) == 0ull) ? 1 : 0;

    const int b = blockIdx.x;
    if (b < NT_W) {
        const void* src; u16* dst; int N, ty;
        if (b < NTQ)                  { src = Wq; dst = WqT; N = 2048; ty = b; }
        else if (b < NTQ + NTK)       { src = Wk; dst = WkT; N = 512;  ty = b - NTQ; }
        else if (b < NTQ + NTK + NTV) { src = Wv; dst = WvT; N = 512;  ty = b - NTQ - NTK; }
        else                          { src = Wo; dst = WoT; N = 2048; ty = b - NTQ - NTK - NTV; }
        const int K = 2048;
        const int ntx = N >> 6;
        const int k0 = (ty / ntx) << 6, n0 = (ty % ntx) << 6;
        const int kk = tid >> 4, cg = (tid & 15) << 2;
        if (isf32) {
            const float* W = (const float*)src;
            #pragma unroll
            for (int it = 0; it < 4; it++) {
                f32x4 v = *(const f32x4*)(W + (size_t)(k0 + kk + it * 16) * N + n0 + cg);
                tile[kk + it * 16][cg + 0] = v[0]; tile[kk + it * 16][cg + 1] = v[1];
                tile[kk + it * 16][cg + 2] = v[2]; tile[kk + it * 16][cg + 3] = v[3];
            }
        } else {
            const u16* W = (const u16*)src;
            #pragma unroll
            for (int it = 0; it < 4; it++) {
                u64 v = *(const u64*)(W + (size_t)(k0 + kk + it * 16) * N + n0 + cg);
                tile[kk + it * 16][cg + 0] = bf2f((u16)(v));
                tile[kk + it * 16][cg + 1] = bf2f((u16)(v >> 16));
                tile[kk + it * 16][cg + 2] = bf2f((u16)(v >> 32));
                tile[kk + it * 16][cg + 3] = bf2f((u16)(v >> 48));
            }
        }
        __syncthreads();
        const int nn = tid >> 2;
        #pragma unroll
        for (int it = 0; it < 2; it++) {
            int kof = ((tid & 3) + it * 4) << 3;
            u16 ob[8];
            #pragma unroll
            for (int j = 0; j < 8; j++) ob[j] = f2bf(tile[kof + j][nn]);
            *(u32x4*)(dst + (size_t)(n0 + nn) * K + k0 + kof) = pack8(ob);
        }
    } else if (b < NT_W + NB_CVT) {
        const long base = ((long)(b - NT_W) * 256 + tid) * 16;
        u16 ob[16];
        if (isf32) {
            const float* p = (const float*)X;
            #pragma unroll
            for (int c = 0; c < 4; c++) {
                f32x4 v = *(const f32x4*)(p + base + c * 4);
                ob[c * 4 + 0] = f2bf(v[0]); ob[c * 4 + 1] = f2bf(v[1]);
                ob[c * 4 + 2] = f2bf(v[2]); ob[c * 4 + 3] = f2bf(v[3]);
            }
        } else {
            const u16* p = (const u16*)X;
            #pragma unroll
            for (int j = 0; j < 16; j++) ob[j] = p[base + j];
        }
        *(u32x4*)(Xbf + base) = pack8(ob);
        *(u32x4*)(Xbf + base + 8) = pack8(ob + 8);
    } else {
        const int b3 = b - NT_W - NB_CVT;
        const bool w1 = (mask[2049] != 0);
        #pragma unroll
        for (int rr = 0; rr < 4; rr++) {
            const int r = b3 * 16 + wave * 4 + rr;
            int cnt = 0;
            if (w1) {
                const u32* row = (const u32*)(mask + (size_t)r * S_LEN);
                #pragma unroll
                for (int i = 0; i < 8; i++) {
                    u32 v = row[lane + i * 64];
                    cnt += (int)(((v & 0x01010101u) * 0x01010101u) >> 24);
                }
            } else {
                const u32* row = (const u32*)mask + (size_t)r * S_LEN;
                #pragma unroll
                for (int i = 0; i < 32; i++) cnt += (row[lane + i * 64] != 0);
            }
            #pragma unroll
            for (int off = 32; off; off >>= 1) cnt += __shfl_down(cnt, off);
            if (lane == 0) start[r] = r + 1 - cnt;
        }
    }
}

// ================= fused QKV projection GEMM =================
// 128x64 tile, 2-phase A-only LDS double-buffer (32KB), B fragments read
// DIRECT from global into ping-pong register sets (prefetched 1 K-step ahead).
__global__ __launch_bounds__(256) void gemm_qkv_kernel(
        const u16* __restrict__ A, const u16* __restrict__ BT,
        u16* __restrict__ Qo, u16* __restrict__ Ko, u16* __restrict__ Vto)
{
    __shared__ char smem[32768];   // A tiles only: 2 x 16KB
    const int tid = threadIdx.x;
    const int wave = tid >> 6, lane = tid & 63, g = lane >> 4, q = lane & 15;
    const int wr = wave >> 1, wc = wave & 1;
    const int gx = gridDim.x, nwg = gx * gridDim.y;
    const int wg = blockIdx.x + blockIdx.y * gx;
    const int swz = (wg & 7) * (nwg >> 3) + (wg >> 3);
    const int m0 = (swz / gx) * 128, n0 = (swz % gx) * 64;
    const int K = HID;

    f32x4 acc[4][2];
    #pragma unroll
    for (int i = 0; i < 4; i++)
        #pragma unroll
        for (int j = 0; j < 2; j++) acc[i][j] = (f32x4){0.f, 0.f, 0.f, 0.f};

    // B row for this lane: BT[n0 + wc*32 + j*16 + q][kbase + kk*32 + g*8]
    const u16* bbase = BT + (size_t)(n0 + wc * 32 + q) * K + g * 8;

    auto stageA = [&](int kt, int b) {     // 4 gload_lds per thread
        const int kbase = kt << 6;
        #pragma unroll
        for (int it = 0; it < 4; ++it) {
            int idx = it * 256 + tid;
            int row = idx >> 3, ch = idx & 7;
            int sch = ch ^ (row & 7);
            gload_lds16(A + (size_t)(m0 + row) * K + kbase + sch * 8,
                        smem + b * 16384 + idx * 16);
        }
    };
    auto loadB = [&](int kt, bf16x8 (&B)[2][2]) {   // 4 x 16B global -> regs
        const int kbase = kt << 6;
        #pragma unroll
        for (int j = 0; j < 2; j++)
            #pragma unroll
            for (int kk = 0; kk < 2; kk++)
                B[j][kk] = *(const bf16x8*)(bbase + (size_t)j * 16 * K + kbase + kk * 32);
    };
    auto compute = [&](int b, const bf16x8 (&B)[2][2]) {
        const char* sa = smem + b * 16384;
        #pragma unroll
        for (int kk = 0; kk < 2; ++kk) {
            bf16x8 af[4];
            #pragma unroll
            for (int i = 0; i < 4; i++) {
                int ra = wr * 64 + i * 16 + q;
                af[i] = *(const bf16x8*)(sa + ra * 128 + (((kk * 4 + g) ^ (ra & 7)) * 16));
            }
            #pragma unroll
            for (int i = 0; i < 4; i++)
                #pragma unroll
                for (int j = 0; j < 2; j++)
                    acc[i][j] = __builtin_amdgcn_mfma_f32_16x16x32_bf16(af[i], B[j][kk], acc[i][j], 0, 0, 0);
        }
    };

    bf16x8 BA[2][2], BB[2][2];     // named ping-pong (static indexing, rule #20)
    const int KT = K >> 6;         // 32 (even)
    loadB(0, BA);
    stageA(0, 0);
    __syncthreads();
    for (int kt = 0; kt < KT; kt += 2) {
        if (kt + 1 < KT) { loadB(kt + 1, BB); stageA(kt + 1, 1); }
        compute(0, BA);            // buf0 holds even tile kt
        __syncthreads();
        if (kt + 2 < KT) { loadB(kt + 2, BA); stageA(kt + 2, 0); }
        if (kt + 1 < KT) {
            compute(1, BB);        // buf1 holds odd tile kt+1
            __syncthreads();
        }
    }

    #pragma unroll
    for (int i = 0; i < 4; i++) {
        #pragma unroll
        for (int j = 0; j < 2; j++) {
            #pragma unroll
            for (int r = 0; r < 4; r++) {
                int m = m0 + wr * 64 + i * 16 + g * 4 + r;
                int n = n0 + wc * 32 + j * 16 + q;
                float v = acc[i][j][r];
                if (n0 < 2048)      Qo[(size_t)m * HID + n] = f2bf(v * QK_SCALE);
                else if (n0 < 2560) Ko[(size_t)m * DKV + (n - 2048)] = f2bf(v);
                else                Vto[(size_t)(n - 2560) * S_LEN + m] = f2bf(v);
            }
        }
    }
}

// ---------- GEMM: C = A[M][K]*B (BT[N][K]); 128x64 tile, 2-phase dbuf (round-9 control) ----------
//  MODE 0: bf16 out   MODE 3: f32 out
template <int MODE>
__global__ __launch_bounds__(256) void gemm_bt_kernel(
        const u16* __restrict__ A, const u16* __restrict__ BT, void* __restrict__ Cv,
        int M, int N, int K, float scale)
{
    __shared__ char smem[49152];
    const int tid = threadIdx.x;
    const int wave = tid >> 6, lane = tid & 63, g = lane >> 4, q = lane & 15;
    const int wr = wave >> 1, wc = wave & 1;
    const int gx = gridDim.x, nwg = gx * gridDim.y;
    const int wg = blockIdx.x + blockIdx.y * gx;
    const int swz = (nwg & 7) == 0 ? ((wg & 7) * (nwg >> 3) + (wg >> 3)) : wg;
    const int m0 = (swz / gx) * 128, n0 = (swz % gx) * 64;

    f32x4 acc[4][2];
    #pragma unroll
    for (int i = 0; i < 4; i++)
        #pragma unroll
        for (int j = 0; j < 2; j++) acc[i][j] = (f32x4){0.f, 0.f, 0.f, 0.f};

    auto stage = [&](int kt, int b) {
        const int kbase = kt << 6;
        #pragma unroll
        for (int it = 0; it < 4; ++it) {
            int idx = it * 256 + tid;
            int row = idx >> 3, ch = idx & 7;
            int sch = ch ^ (row & 7);
            gload_lds16(A + (size_t)(m0 + row) * K + kbase + sch * 8,
                        smem + b * 16384 + idx * 16);
        }
        #pragma unroll
        for (int it = 0; it < 2; ++it) {
            int idx = it * 256 + tid;
            int row = idx >> 3, ch = idx & 7;
            int sch = ch ^ (row & 7);
            gload_lds16(BT + (size_t)(n0 + row) * K + kbase + sch * 8,
                        smem + 32768 + b * 8192 + idx * 16);
        }
    };

    const int KT = K >> 6;
    stage(0, 0);
    __syncthreads();
    int cur = 0;
    for (int kt = 0; kt < KT; ++kt) {
        if (kt + 1 < KT) stage(kt + 1, cur ^ 1);
        const char* sa = smem + cur * 16384;
        const char* sb = smem + 32768 + cur * 8192;
        #pragma unroll
        for (int kk = 0; kk < 2; ++kk) {
            bf16x8 af[4], bfr[2];
            #pragma unroll
            for (int i = 0; i < 4; i++) {
                int ra = wr * 64 + i * 16 + q;
                af[i] = *(const bf16x8*)(sa + ra * 128 + (((kk * 4 + g) ^ (ra & 7)) * 16));
            }
            #pragma unroll
            for (int j = 0; j < 2; j++) {
                int rb = wc * 32 + j * 16 + q;
                bfr[j] = *(const bf16x8*)(sb + rb * 128 + (((kk * 4 + g) ^ (rb & 7)) * 16));
            }
            #pragma unroll
            for (int i = 0; i < 4; i++)
                #pragma unroll
                for (int j = 0; j < 2; j++)
                    acc[i][j] = __builtin_amdgcn_mfma_f32_16x16x32_bf16(af[i], bfr[j], acc[i][j], 0, 0, 0);
        }
        __syncthreads();
        cur ^= 1;
    }
    #pragma unroll
    for (int i = 0; i < 4; i++) {
        #pragma unroll
        for (int j = 0; j < 2; j++) {
            #pragma unroll
            for (int r = 0; r < 4; r++) {
                int m = m0 + wr * 64 + i * 16 + g * 4 + r;
                int n = n0 + wc * 32 + j * 16 + q;
                float v = acc[i][j][r] * scale;
                if (MODE == 3) ((float*)Cv)[(size_t)m * N + n] = v;
                else           ((u16*)Cv)[(size_t)m * N + n] = f2bf(v);
            }
        }
    }
}

// ================= adaptive-window flash attention, 32x32 swapped-operand =================
// (unchanged: zero LDS, in-register softmax)
__global__ __launch_bounds__(256, 1) void attn_kernel(
        const u16* __restrict__ Q, const u16* __restrict__ Kb,
        const u16* __restrict__ Vt, u16* __restrict__ O, const int* __restrict__ start)
{
    const int tid = threadIdx.x, wave = tid >> 6, lane = tid & 63;
    const int q = lane & 31, hi = lane >> 5;
    const int h = blockIdx.y, hk = h >> 2;
    const int r0 = blockIdx.x * 128 + wave * 32;
    const int qrow = r0 + q;

    const u16* qp = Q + (size_t)qrow * HID + h * HD + hi * 8;
    bf16x8 Qf[8];
    #pragma unroll
    for (int kc = 0; kc < 8; kc++) Qf[kc] = *(const bf16x8*)(qp + kc * 16);

    const int startq = start[qrow];
    int jlo = startq;
    #pragma unroll
    for (int off = 1; off < 32; off <<= 1) jlo = min(jlo, __shfl_xor(jlo, off));
    const int jend = r0 + 31;

    float m = -INFINITY, l = 0.f;
    f32x16 o[4];
    #pragma unroll
    for (int dt = 0; dt < 4; dt++) o[dt] = (f32x16){};

    for (int j0 = (jlo & ~31); j0 <= jend; j0 += 32) {
        const u16* kp = Kb + (size_t)(j0 + q) * DKV + hk * HD + hi * 8;
        bf16x8 Kf[8];
        #pragma unroll
        for (int kc = 0; kc < 8; kc++) Kf[kc] = *(const bf16x8*)(kp + kc * 16);
        const u16* vp = Vt + (size_t)(hk * HD + q) * S_LEN + j0 + hi * 8;
        bf16x8 Vf[8];
        #pragma unroll
        for (int dt = 0; dt < 4; dt++)
            #pragma unroll
            for (int c = 0; c < 2; c++)
                Vf[dt * 2 + c] = *(const bf16x8*)(vp + (size_t)dt * 32 * S_LEN + c * 16);

        f32x16 s = (f32x16){};
        #pragma unroll
        for (int kc = 0; kc < 8; kc++)
            s = __builtin_amdgcn_mfma_f32_32x32x16_bf16(Kf[kc], Qf[kc], s, 0, 0, 0);

        float sv[16];
        float pmax = -INFINITY;
        #pragma unroll
        for (int r = 0; r < 16; r++) {
            int j = j0 + (r & 3) + 8 * (r >> 2) + 4 * hi;
            float x = (j <= qrow && j >= startq) ? s[r] : -INFINITY;
            sv[r] = x;
            pmax = fmaxf(pmax, x);
        }
        pmax = pairmax32(pmax);

        bool defer = __all(pmax <= m + 8.f);
        float mnew = m;
        if (!defer) {
            mnew = fmaxf(m, pmax);
            float corr = (m == -INFINITY) ? 0.f : __expf(m - mnew);
            l *= corr;
            #pragma unroll
            for (int dt = 0; dt < 4; dt++)
                #pragma unroll
                for (int r = 0; r < 16; r++) o[dt][r] *= corr;
            m = mnew;
        }

        float ps = 0.f;
        u16 pb[16];
        #pragma unroll
        for (int r = 0; r < 16; r++) {
            float p = (sv[r] == -INFINITY) ? 0.f : __expf(sv[r] - mnew);
            ps += p;
            pb[r] = f2bf(p);
        }
        l += pairsum32(ps);

        u32 w[8];
        #pragma unroll
        for (int i = 0; i < 8; i++) w[i] = (u32)pb[2 * i] | ((u32)pb[2 * i + 1] << 16);
        u32 x0, x1, y0, y1;
        plswap(w[0], w[2], x0, x1); plswap(w[1], w[3], y0, y1);
        u32x4 c0w = {x0, y0, x1, y1};
        bf16x8 P0 = __builtin_bit_cast(bf16x8, c0w);
        plswap(w[4], w[6], x0, x1); plswap(w[5], w[7], y0, y1);
        u32x4 c1w = {x0, y0, x1, y1};
        bf16x8 P1 = __builtin_bit_cast(bf16x8, c1w);

        #pragma unroll
        for (int dt = 0; dt < 4; dt++) {
            o[dt] = __builtin_amdgcn_mfma_f32_32x32x16_bf16(Vf[dt * 2 + 0], P0, o[dt], 0, 0, 0);
            o[dt] = __builtin_amdgcn_mfma_f32_32x32x16_bf16(Vf[dt * 2 + 1], P1, o[dt], 0, 0, 0);
        }
    }

    float inv = 1.0f / l;
    u16* op = O + (size_t)qrow * HID + h * HD + 4 * hi;
    #pragma unroll
    for (int dt = 0; dt < 4; dt++) {
        #pragma unroll
        for (int rb = 0; rb < 16; rb += 4) {
            u64 wd = (u64)f2bf(o[dt][rb + 0] * inv) |
                     ((u64)f2bf(o[dt][rb + 1] * inv) << 16) |
                     ((u64)f2bf(o[dt][rb + 2] * inv) << 32) |
                     ((u64)f2bf(o[dt][rb + 3] * inv) << 48);
            *(u64*)(op + dt * 32 + 2 * rb) = wd;
        }
    }
}

// ---------- launch ----------
extern "C" void kernel_launch(void* const* d_in, const int* in_sizes, int n_in,
                              void* d_out, int out_size, void* d_ws, size_t ws_size,
                              hipStream_t stream)
{
    char* ws = (char*)d_ws;
    const size_t MB = 1024 * 1024;
    int* start = (int*)(ws + 1024);
    u16* Xbf = (u16*)(ws + 16384);
    u16* WqT = (u16*)(ws + 16384 + 8 * MB);    // [2048][2048]
    u16* WkT = (u16*)(ws + 16384 + 16 * MB);   // [512][2048]
    u16* WvT = (u16*)(ws + 16384 + 18 * MB);   // [512][2048]
    u16* WoT = (u16*)(ws + 16384 + 20 * MB);
    u16* Qbf = (u16*)(ws + 16384 + 28 * MB);
    u16* Kbf = (u16*)(ws + 16384 + 36 * MB);
    u16* Vtb = (u16*)(ws + 16384 + 38 * MB);
    u16* Obf = (u16*)(ws + 16384 + 40 * MB);

    const void* X  = d_in[0];
    const unsigned char* mask = (const unsigned char*)d_in[1];
    const void* Wq = d_in[2];
    const void* Wk = d_in[3];
    const void* Wv = d_in[4];
    const void* Wo = d_in[5];

    prep_kernel<<<NB_PREP, 256, 0, stream>>>(
        (const u32*)X, mask, Wq, Wk, Wv, Wo, Xbf, WqT, WkT, WvT, WoT, start);

    gemm_qkv_kernel<<<dim3(48, HID / 128), 256, 0, stream>>>(Xbf, WqT, Qbf, Kbf, Vtb);

    attn_kernel<<<dim3(S_LEN / 128, NH), 256, 0, stream>>>(Qbf, Kbf, Vtb, Obf, start);

    gemm_bt_kernel<3><<<dim3(HID / 64, S_LEN / 128), 256, 0, stream>>>(Obf, WoT, d_out, S_LEN, HID, HID, 1.f);
}

// Round 12
// 106.563 us; speedup vs baseline: 1.3959x; 1.3959x over previous
//
#include <hip/hip_runtime.h>
#include <hip/hip_bf16.h>

// ---------- types ----------
typedef __attribute__((ext_vector_type(4)))  float f32x4;
typedef __attribute__((ext_vector_type(16))) float f32x16;
typedef __attribute__((ext_vector_type(8)))  short bf16x8;   // 8 bf16 in 4 VGPRs
typedef unsigned short u16;
typedef unsigned int   u32;
typedef unsigned long long u64;
typedef __attribute__((ext_vector_type(2))) u32 u32x2;
typedef __attribute__((ext_vector_type(4))) u32 u32x4;

#define S_LEN 2048
#define HID   2048
#define NH    16
#define NKV   4
#define HD    128
#define DKV   512          // NKV*HD
#define QK_SCALE 0.08838834764831845f   // 1/sqrt(128)

__device__ __forceinline__ u16 f2bf(float x) {              // RNE f32 -> bf16 bits
    u32 u = __builtin_bit_cast(u32, x);
    u32 r = (u + 0x7fffu + ((u >> 16) & 1u)) >> 16;
    return (u16)r;
}
__device__ __forceinline__ float bf2f(u16 b) {
    u32 u = ((u32)b) << 16;
    return __builtin_bit_cast(float, u);
}
__device__ __forceinline__ void gload_lds16(const void* g, void* l) {
    __builtin_amdgcn_global_load_lds(
        (const __attribute__((address_space(1))) u32*)g,
        (__attribute__((address_space(3))) u32*)l, 16, 0, 0);
}
__device__ __forceinline__ u32x4 pack8(const u16* o) {
    u32x4 r;
    r[0] = (u32)o[0] | ((u32)o[1] << 16);
    r[1] = (u32)o[2] | ((u32)o[3] << 16);
    r[2] = (u32)o[4] | ((u32)o[5] << 16);
    r[3] = (u32)o[6] | ((u32)o[7] << 16);
    return r;
}

// lane pair (L, L^32) exchange: x0/x1 per v_permlane32_swap semantics
__device__ __forceinline__ void plswap(u32 a, u32 b, u32& x0, u32& x1) {
#if __has_builtin(__builtin_amdgcn_permlane32_swap)
    u32x2 r = __builtin_amdgcn_permlane32_swap(a, b, false, false);
    x0 = r[0]; x1 = r[1];
#else
    u32 oa = (u32)__shfl_xor((int)a, 32);
    u32 ob = (u32)__shfl_xor((int)b, 32);
    int hi = (threadIdx.x & 63) >> 5;
    x0 = hi ? ob : a;
    x1 = hi ? b : oa;
#endif
}
__device__ __forceinline__ float pairmax32(float v) {
    u32 x0, x1; plswap(__builtin_bit_cast(u32, v), __builtin_bit_cast(u32, v), x0, x1);
    return fmaxf(__builtin_bit_cast(float, x0), __builtin_bit_cast(float, x1));
}
__device__ __forceinline__ float pairsum32(float v) {
    u32 x0, x1; plswap(__builtin_bit_cast(u32, v), __builtin_bit_cast(u32, v), x0, x1);
    return __builtin_bit_cast(float, x0) + __builtin_bit_cast(float, x1);
}

// ================= fused preprocessing (unchanged) =================
#define NTQ 1024
#define NTK 256
#define NTV 256
#define NTO 1024
#define NT_W (NTQ + NTK + NTV + NTO)          // 2560
#define NB_CVT 1024
#define NB_START 128
#define NB_PREP (NT_W + NB_CVT + NB_START)    // 3712

__global__ __launch_bounds__(256) void prep_kernel(
        const u32* __restrict__ X, const unsigned char* __restrict__ mask,
        const void* __restrict__ Wq, const void* __restrict__ Wk,
        const void* __restrict__ Wv, const void* __restrict__ Wo,
        u16* __restrict__ Xbf, u16* __restrict__ WqT, u16* __restrict__ WkT,
        u16* __restrict__ WvT, u16* __restrict__ WoT, int* __restrict__ start)
{
    __shared__ float tile[64][65];
    const int tid = threadIdx.x, lane = tid & 63, wave = tid >> 6;

    int big = 0, nz = 0;
    #pragma unroll
    for (int i = 0; i < 4; i++) {
        u32 v = X[lane + i * 64];
        u16 lo = (u16)(v & 0xffffu);
        int e = (lo >> 7) & 0xff;
        big |= (e >= 0x83);
        nz  |= (lo != 0);
    }
    const int isf32 = (__ballot(big) != 0ull || __ballot(nz) == 0ull) ? 1 : 0;

    const int b = blockIdx.x;
    if (b < NT_W) {
        const void* src; u16* dst; int N, ty;
        if (b < NTQ)                  { src = Wq; dst = WqT; N = 2048; ty = b; }
        else if (b < NTQ + NTK)       { src = Wk; dst = WkT; N = 512;  ty = b - NTQ; }
        else if (b < NTQ + NTK + NTV) { src = Wv; dst = WvT; N = 512;  ty = b - NTQ - NTK; }
        else                          { src = Wo; dst = WoT; N = 2048; ty = b - NTQ - NTK - NTV; }
        const int K = 2048;
        const int ntx = N >> 6;
        const int k0 = (ty / ntx) << 6, n0 = (ty % ntx) << 6;
        const int kk = tid >> 4, cg = (tid & 15) << 2;
        if (isf32) {
            const float* W = (const float*)src;
            #pragma unroll
            for (int it = 0; it < 4; it++) {
                f32x4 v = *(const f32x4*)(W + (size_t)(k0 + kk + it * 16) * N + n0 + cg);
                tile[kk + it * 16][cg + 0] = v[0]; tile[kk + it * 16][cg + 1] = v[1];
                tile[kk + it * 16][cg + 2] = v[2]; tile[kk + it * 16][cg + 3] = v[3];
            }
        } else {
            const u16* W = (const u16*)src;
            #pragma unroll
            for (int it = 0; it < 4; it++) {
                u64 v = *(const u64*)(W + (size_t)(k0 + kk + it * 16) * N + n0 + cg);
                tile[kk + it * 16][cg + 0] = bf2f((u16)(v));
                tile[kk + it * 16][cg + 1] = bf2f((u16)(v >> 16));
                tile[kk + it * 16][cg + 2] = bf2f((u16)(v >> 32));
                tile[kk + it * 16][cg + 3] = bf2f((u16)(v >> 48));
            }
        }
        __syncthreads();
        const int nn = tid >> 2;
        #pragma unroll
        for (int it = 0; it < 2; it++) {
            int kof = ((tid & 3) + it * 4) << 3;
            u16 ob[8];
            #pragma unroll
            for (int j = 0; j < 8; j++) ob[j] = f2bf(tile[kof + j][nn]);
            *(u32x4*)(dst + (size_t)(n0 + nn) * K + k0 + kof) = pack8(ob);
        }
    } else if (b < NT_W + NB_CVT) {
        const long base = ((long)(b - NT_W) * 256 + tid) * 16;
        u16 ob[16];
        if (isf32) {
            const float* p = (const float*)X;
            #pragma unroll
            for (int c = 0; c < 4; c++) {
                f32x4 v = *(const f32x4*)(p + base + c * 4);
                ob[c * 4 + 0] = f2bf(v[0]); ob[c * 4 + 1] = f2bf(v[1]);
                ob[c * 4 + 2] = f2bf(v[2]); ob[c * 4 + 3] = f2bf(v[3]);
            }
        } else {
            const u16* p = (const u16*)X;
            #pragma unroll
            for (int j = 0; j < 16; j++) ob[j] = p[base + j];
        }
        *(u32x4*)(Xbf + base) = pack8(ob);
        *(u32x4*)(Xbf + base + 8) = pack8(ob + 8);
    } else {
        const int b3 = b - NT_W - NB_CVT;
        const bool w1 = (mask[2049] != 0);
        #pragma unroll
        for (int rr = 0; rr < 4; rr++) {
            const int r = b3 * 16 + wave * 4 + rr;
            int cnt = 0;
            if (w1) {
                const u32* row = (const u32*)(mask + (size_t)r * S_LEN);
                #pragma unroll
                for (int i = 0; i < 8; i++) {
                    u32 v = row[lane + i * 64];
                    cnt += (int)(((v & 0x01010101u) * 0x01010101u) >> 24);
                }
            } else {
                const u32* row = (const u32*)mask + (size_t)r * S_LEN;
                #pragma unroll
                for (int i = 0; i < 32; i++) cnt += (row[lane + i * 64] != 0);
            }
            #pragma unroll
            for (int off = 32; off; off >>= 1) cnt += __shfl_down(cnt, off);
            if (lane == 0) start[r] = r + 1 - cnt;
        }
    }
}

// ================= fused QKV projection GEMM (round-9 structure) =================
// 128x64 tile, 2-phase dbuf (48KB), XCD swizzle. Epilogue stores Q/K/V in
// MFMA-FRAGMENT layout [head][tile32][kc][lane][8] so attn loads are coalesced.
__global__ __launch_bounds__(256) void gemm_qkv_kernel(
        const u16* __restrict__ A, const u16* __restrict__ BT,
        u16* __restrict__ Qf, u16* __restrict__ Kf, u16* __restrict__ Vf)
{
    __shared__ char smem[49152];
    const int tid = threadIdx.x;
    const int wave = tid >> 6, lane = tid & 63, g = lane >> 4, q = lane & 15;
    const int wr = wave >> 1, wc = wave & 1;
    const int gx = gridDim.x, nwg = gx * gridDim.y;
    const int wg = blockIdx.x + blockIdx.y * gx;
    const int swz = (wg & 7) * (nwg >> 3) + (wg >> 3);
    const int m0 = (swz / gx) * 128, n0 = (swz % gx) * 64;
    const int K = HID;

    f32x4 acc[4][2];
    #pragma unroll
    for (int i = 0; i < 4; i++)
        #pragma unroll
        for (int j = 0; j < 2; j++) acc[i][j] = (f32x4){0.f, 0.f, 0.f, 0.f};

    auto stage = [&](int kt, int b) {
        const int kbase = kt << 6;
        #pragma unroll
        for (int it = 0; it < 4; ++it) {
            int idx = it * 256 + tid;
            int row = idx >> 3, ch = idx & 7;
            int sch = ch ^ (row & 7);
            gload_lds16(A + (size_t)(m0 + row) * K + kbase + sch * 8,
                        smem + b * 16384 + idx * 16);
        }
        #pragma unroll
        for (int it = 0; it < 2; ++it) {
            int idx = it * 256 + tid;
            int row = idx >> 3, ch = idx & 7;
            int sch = ch ^ (row & 7);
            gload_lds16(BT + (size_t)(n0 + row) * K + kbase + sch * 8,
                        smem + 32768 + b * 8192 + idx * 16);
        }
    };

    const int KT = K >> 6;
    stage(0, 0);
    __syncthreads();
    int cur = 0;
    for (int kt = 0; kt < KT; ++kt) {
        if (kt + 1 < KT) stage(kt + 1, cur ^ 1);
        const char* sa = smem + cur * 16384;
        const char* sb = smem + 32768 + cur * 8192;
        #pragma unroll
        for (int kk = 0; kk < 2; ++kk) {
            bf16x8 af[4], bfr[2];
            #pragma unroll
            for (int i = 0; i < 4; i++) {
                int ra = wr * 64 + i * 16 + q;
                af[i] = *(const bf16x8*)(sa + ra * 128 + (((kk * 4 + g) ^ (ra & 7)) * 16));
            }
            #pragma unroll
            for (int j = 0; j < 2; j++) {
                int rb = wc * 32 + j * 16 + q;
                bfr[j] = *(const bf16x8*)(sb + rb * 128 + (((kk * 4 + g) ^ (rb & 7)) * 16));
            }
            #pragma unroll
            for (int i = 0; i < 4; i++)
                #pragma unroll
                for (int j = 0; j < 2; j++)
                    acc[i][j] = __builtin_amdgcn_mfma_f32_16x16x32_bf16(af[i], bfr[j], acc[i][j], 0, 0, 0);
        }
        __syncthreads();
        cur ^= 1;
    }
    // ---- epilogue: fragment-layout stores ----
    // Q/K frag: [(h|hk)][t=m>>5][kc=dd>>4][lane=(m&31)+32*((dd>>3)&1)][e=dd&7]
    // V  frag:  [hk][t=m>>5][dt*2+c][lane=(dd&31)+32*((jj>>3)&1)][e=jj&7], jj=m&31
    #pragma unroll
    for (int i = 0; i < 4; i++) {
        #pragma unroll
        for (int j = 0; j < 2; j++) {
            #pragma unroll
            for (int r = 0; r < 4; r++) {
                int m = m0 + wr * 64 + i * 16 + g * 4 + r;
                int n = n0 + wc * 32 + j * 16 + q;
                float v = acc[i][j][r];
                int t = m >> 5, jj = m & 31;
                if (n0 < 2048) {
                    int h = n >> 7, dd = n & 127;
                    int kc = dd >> 4, hi8 = (dd >> 3) & 1, e = dd & 7;
                    Qf[(size_t)h * 262144 + t * 4096 + kc * 512 + (jj + hi8 * 32) * 8 + e]
                        = f2bf(v * QK_SCALE);
                } else if (n0 < 2560) {
                    int d = n - 2048;
                    int hkk = d >> 7, dd = d & 127;
                    int kc = dd >> 4, hi8 = (dd >> 3) & 1, e = dd & 7;
                    Kf[(size_t)hkk * 262144 + t * 4096 + kc * 512 + (jj + hi8 * 32) * 8 + e]
                        = f2bf(v);
                } else {
                    int d = n - 2560;
                    int hkk = d >> 7, dd = d & 127;
                    int dt = dd >> 5, l31 = dd & 31;
                    int c = (jj >> 4) & 1, hi8 = (jj >> 3) & 1, e = jj & 7;
                    Vf[(size_t)hkk * 262144 + t * 4096 + (dt * 2 + c) * 512 + (l31 + hi8 * 32) * 8 + e]
                        = f2bf(v);
                }
            }
        }
    }
}

// ---------- GEMM: C = A[M][K]*B (BT[N][K]); 128x64 tile, 2-phase dbuf (round-9) ----------
template <int MODE>
__global__ __launch_bounds__(256) void gemm_bt_kernel(
        const u16* __restrict__ A, const u16* __restrict__ BT, void* __restrict__ Cv,
        int M, int N, int K, float scale)
{
    __shared__ char smem[49152];
    const int tid = threadIdx.x;
    const int wave = tid >> 6, lane = tid & 63, g = lane >> 4, q = lane & 15;
    const int wr = wave >> 1, wc = wave & 1;
    const int gx = gridDim.x, nwg = gx * gridDim.y;
    const int wg = blockIdx.x + blockIdx.y * gx;
    const int swz = (nwg & 7) == 0 ? ((wg & 7) * (nwg >> 3) + (wg >> 3)) : wg;
    const int m0 = (swz / gx) * 128, n0 = (swz % gx) * 64;

    f32x4 acc[4][2];
    #pragma unroll
    for (int i = 0; i < 4; i++)
        #pragma unroll
        for (int j = 0; j < 2; j++) acc[i][j] = (f32x4){0.f, 0.f, 0.f, 0.f};

    auto stage = [&](int kt, int b) {
        const int kbase = kt << 6;
        #pragma unroll
        for (int it = 0; it < 4; ++it) {
            int idx = it * 256 + tid;
            int row = idx >> 3, ch = idx & 7;
            int sch = ch ^ (row & 7);
            gload_lds16(A + (size_t)(m0 + row) * K + kbase + sch * 8,
                        smem + b * 16384 + idx * 16);
        }
        #pragma unroll
        for (int it = 0; it < 2; ++it) {
            int idx = it * 256 + tid;
            int row = idx >> 3, ch = idx & 7;
            int sch = ch ^ (row & 7);
            gload_lds16(BT + (size_t)(n0 + row) * K + kbase + sch * 8,
                        smem + 32768 + b * 8192 + idx * 16);
        }
    };

    const int KT = K >> 6;
    stage(0, 0);
    __syncthreads();
    int cur = 0;
    for (int kt = 0; kt < KT; ++kt) {
        if (kt + 1 < KT) stage(kt + 1, cur ^ 1);
        const char* sa = smem + cur * 16384;
        const char* sb = smem + 32768 + cur * 8192;
        #pragma unroll
        for (int kk = 0; kk < 2; ++kk) {
            bf16x8 af[4], bfr[2];
            #pragma unroll
            for (int i = 0; i < 4; i++) {
                int ra = wr * 64 + i * 16 + q;
                af[i] = *(const bf16x8*)(sa + ra * 128 + (((kk * 4 + g) ^ (ra & 7)) * 16));
            }
            #pragma unroll
            for (int j = 0; j < 2; j++) {
                int rb = wc * 32 + j * 16 + q;
                bfr[j] = *(const bf16x8*)(sb + rb * 128 + (((kk * 4 + g) ^ (rb & 7)) * 16));
            }
            #pragma unroll
            for (int i = 0; i < 4; i++)
                #pragma unroll
                for (int j = 0; j < 2; j++)
                    acc[i][j] = __builtin_amdgcn_mfma_f32_16x16x32_bf16(af[i], bfr[j], acc[i][j], 0, 0, 0);
        }
        __syncthreads();
        cur ^= 1;
    }
    #pragma unroll
    for (int i = 0; i < 4; i++) {
        #pragma unroll
        for (int j = 0; j < 2; j++) {
            #pragma unroll
            for (int r = 0; r < 4; r++) {
                int m = m0 + wr * 64 + i * 16 + g * 4 + r;
                int n = n0 + wc * 32 + j * 16 + q;
                float v = acc[i][j][r] * scale;
                if (MODE == 3) ((float*)Cv)[(size_t)m * N + n] = v;
                else           ((u16*)Cv)[(size_t)m * N + n] = f2bf(v);
            }
        }
    }
}

// ================= adaptive-window flash attention, fragment-layout loads =================
// All Q/K/V reads are wave-contiguous 1KB loads from fragment buffers.
__global__ __launch_bounds__(256, 1) void attn_kernel(
        const u16* __restrict__ Q, const u16* __restrict__ Kb,
        const u16* __restrict__ Vt, u16* __restrict__ O, const int* __restrict__ start)
{
    const int tid = threadIdx.x, wave = tid >> 6, lane = tid & 63;
    const int q = lane & 31, hi = lane >> 5;
    const int h = blockIdx.y, hk = h >> 2;
    const int r0 = blockIdx.x * 128 + wave * 32;
    const int qrow = r0 + q;

    // Q fragments: coalesced read from Qfrag[h][r0>>5][kc][lane][8]
    const u16* qf = Q + (size_t)h * 262144 + (r0 >> 5) * 4096 + lane * 8;
    bf16x8 Qf[8];
    #pragma unroll
    for (int kc = 0; kc < 8; kc++) Qf[kc] = *(const bf16x8*)(qf + kc * 512);

    const int startq = start[qrow];
    int jlo = startq;
    #pragma unroll
    for (int off = 1; off < 32; off <<= 1) jlo = min(jlo, __shfl_xor(jlo, off));
    const int jend = r0 + 31;

    float m = -INFINITY, l = 0.f;
    f32x16 o[4];
    #pragma unroll
    for (int dt = 0; dt < 4; dt++) o[dt] = (f32x16){};

    const u16* kfb = Kb + (size_t)hk * 262144 + lane * 8;
    const u16* vfb = Vt + (size_t)hk * 262144 + lane * 8;

    for (int j0 = (jlo & ~31); j0 <= jend; j0 += 32) {
        const int t = j0 >> 5;
        const u16* kf = kfb + t * 4096;
        bf16x8 Kf[8];
        #pragma unroll
        for (int kc = 0; kc < 8; kc++) Kf[kc] = *(const bf16x8*)(kf + kc * 512);
        const u16* vf = vfb + t * 4096;
        bf16x8 Vf[8];
        #pragma unroll
        for (int idx = 0; idx < 8; idx++) Vf[idx] = *(const bf16x8*)(vf + idx * 512);

        f32x16 s = (f32x16){};
        #pragma unroll
        for (int kc = 0; kc < 8; kc++)
            s = __builtin_amdgcn_mfma_f32_32x32x16_bf16(Kf[kc], Qf[kc], s, 0, 0, 0);

        float sv[16];
        float pmax = -INFINITY;
        #pragma unroll
        for (int r = 0; r < 16; r++) {
            int j = j0 + (r & 3) + 8 * (r >> 2) + 4 * hi;
            float x = (j <= qrow && j >= startq) ? s[r] : -INFINITY;
            sv[r] = x;
            pmax = fmaxf(pmax, x);
        }
        pmax = pairmax32(pmax);

        bool defer = __all(pmax <= m + 8.f);
        float mnew = m;
        if (!defer) {
            mnew = fmaxf(m, pmax);
            float corr = (m == -INFINITY) ? 0.f : __expf(m - mnew);
            l *= corr;
            #pragma unroll
            for (int dt = 0; dt < 4; dt++)
                #pragma unroll
                for (int r = 0; r < 16; r++) o[dt][r] *= corr;
            m = mnew;
        }

        float ps = 0.f;
        u16 pb[16];
        #pragma unroll
        for (int r = 0; r < 16; r++) {
            float p = (sv[r] == -INFINITY) ? 0.f : __expf(sv[r] - mnew);
            ps += p;
            pb[r] = f2bf(p);
        }
        l += pairsum32(ps);

        u32 w[8];
        #pragma unroll
        for (int i = 0; i < 8; i++) w[i] = (u32)pb[2 * i] | ((u32)pb[2 * i + 1] << 16);
        u32 x0, x1, y0, y1;
        plswap(w[0], w[2], x0, x1); plswap(w[1], w[3], y0, y1);
        u32x4 c0w = {x0, y0, x1, y1};
        bf16x8 P0 = __builtin_bit_cast(bf16x8, c0w);
        plswap(w[4], w[6], x0, x1); plswap(w[5], w[7], y0, y1);
        u32x4 c1w = {x0, y0, x1, y1};
        bf16x8 P1 = __builtin_bit_cast(bf16x8, c1w);

        #pragma unroll
        for (int dt = 0; dt < 4; dt++) {
            o[dt] = __builtin_amdgcn_mfma_f32_32x32x16_bf16(Vf[dt * 2 + 0], P0, o[dt], 0, 0, 0);
            o[dt] = __builtin_amdgcn_mfma_f32_32x32x16_bf16(Vf[dt * 2 + 1], P1, o[dt], 0, 0, 0);
        }
    }

    float inv = 1.0f / l;
    u16* op = O + (size_t)qrow * HID + h * HD + 4 * hi;
    #pragma unroll
    for (int dt = 0; dt < 4; dt++) {
        #pragma unroll
        for (int rb = 0; rb < 16; rb += 4) {
            u64 wd = (u64)f2bf(o[dt][rb + 0] * inv) |
                     ((u64)f2bf(o[dt][rb + 1] * inv) << 16) |
                     ((u64)f2bf(o[dt][rb + 2] * inv) << 32) |
                     ((u64)f2bf(o[dt][rb + 3] * inv) << 48);
            *(u64*)(op + dt * 32 + 2 * rb) = wd;
        }
    }
}

// ---------- launch ----------
extern "C" void kernel_launch(void* const* d_in, const int* in_sizes, int n_in,
                              void* d_out, int out_size, void* d_ws, size_t ws_size,
                              hipStream_t stream)
{
    char* ws = (char*)d_ws;
    const size_t MB = 1024 * 1024;
    int* start = (int*)(ws + 1024);
    u16* Xbf = (u16*)(ws + 16384);
    u16* WqT = (u16*)(ws + 16384 + 8 * MB);    // [2048][2048]
    u16* WkT = (u16*)(ws + 16384 + 16 * MB);   // [512][2048]
    u16* WvT = (u16*)(ws + 16384 + 18 * MB);   // [512][2048]
    u16* WoT = (u16*)(ws + 16384 + 20 * MB);
    u16* Qfr = (u16*)(ws + 16384 + 28 * MB);   // Q fragment buffer, 8MB
    u16* Kfr = (u16*)(ws + 16384 + 36 * MB);   // K fragment buffer, 2MB
    u16* Vfr = (u16*)(ws + 16384 + 38 * MB);   // V fragment buffer, 2MB
    u16* Obf = (u16*)(ws + 16384 + 40 * MB);

    const void* X  = d_in[0];
    const unsigned char* mask = (const unsigned char*)d_in[1];
    const void* Wq = d_in[2];
    const void* Wk = d_in[3];
    const void* Wv = d_in[4];
    const void* Wo = d_in[5];

    prep_kernel<<<NB_PREP, 256, 0, stream>>>(
        (const u32*)X, mask, Wq, Wk, Wv, Wo, Xbf, WqT, WkT, WvT, WoT, start);

    gemm_qkv_kernel<<<dim3(48, HID / 128), 256, 0, stream>>>(Xbf, WqT, Qfr, Kfr, Vfr);

    attn_kernel<<<dim3(S_LEN / 128, NH), 256, 0, stream>>>(Qfr, Kfr, Vfr, Obf, start);

    gemm_bt_kernel<3><<<dim3(HID / 64, S_LEN / 128), 256, 0, stream>>>(Obf, WoT, d_out, S_LEN, HID, HID, 1.f);
}